// Round 1
// baseline (496.177 us; speedup 1.0000x reference)
//
#include <hip/hip_runtime.h>
#include <stdint.h>

typedef __attribute__((ext_vector_type(4))) float f32x4;
typedef __attribute__((ext_vector_type(8))) __bf16 bf16x8;
typedef __attribute__((ext_vector_type(4))) unsigned short u16x4;

static __device__ __forceinline__ unsigned short f2bf(float f) {
  union { float f; uint32_t u; } v; v.f = f;
  return (unsigned short)((v.u + 0x7fffu + ((v.u >> 16) & 1u)) >> 16);  // RNE
}

// ---------------------------------------------------------------------------
// Kernel 1: Wc[k][n] = sum_c W_kv[k][512+c] * W_proj[c][n]   (fp32 accum)
// Output: packed bf16, laid out as the exact LDS byte image the main GEMM
// stages with global_load_lds:
//   tile (ct=n>>7, ks=k>>6) of 16384 bytes; within tile, element (col=n&127,
//   kk=k&63) lives at byte ((col*128 + kk*2) ^ ((col&7)<<4)).
// ---------------------------------------------------------------------------
__global__ __launch_bounds__(256) void prep_wc(
    const float* __restrict__ W_kv, const float* __restrict__ W_proj,
    unsigned short* __restrict__ WcPack)
{
  const int t = threadIdx.x;
  const int k0 = blockIdx.x * 4;                 // 128 blocks cover k 0..511
  const int col = t & 127;
  const int n = col * 4;
  const int kj = __builtin_amdgcn_readfirstlane((t >> 7) * 2);  // wave-uniform
  const float* __restrict__ wv0 = W_kv + (size_t)(k0 + kj) * 1024 + 512;
  const float* __restrict__ wv1 = W_kv + (size_t)(k0 + kj + 1) * 1024 + 512;

  float acc0[4] = {0.f, 0.f, 0.f, 0.f};
  float acc1[4] = {0.f, 0.f, 0.f, 0.f};
  #pragma unroll 4
  for (int c = 0; c < 512; ++c) {
    const float a0 = wv0[c];
    const float a1 = wv1[c];
    const f32x4 p = *reinterpret_cast<const f32x4*>(W_proj + (size_t)c * 512 + n);
    #pragma unroll
    for (int i = 0; i < 4; ++i) { acc0[i] += a0 * p[i]; acc1[i] += a1 * p[i]; }
  }

  #pragma unroll
  for (int j = 0; j < 2; ++j) {
    const int k = k0 + kj + j;
    const int ks = k >> 6, kk = k & 63;
    const float* a = j ? acc1 : acc0;
    #pragma unroll
    for (int i = 0; i < 4; ++i) {
      const int nn = n + i;
      const int ct = nn >> 7, cc = nn & 127;
      const uint32_t boff = (uint32_t)(((cc << 7) + (kk << 1)) ^ ((cc & 7) << 4));
      WcPack[(size_t)(((ct << 3) + ks) << 13) + (boff >> 1)] = f2bf(a[i]);
    }
  }
}

// ---------------------------------------------------------------------------
// Kernel 2: out[m][n] = x[m*1024 + k] (k<512) @ Wc[k][n] + b_proj[n]
// 128x128 tile, BK=64, 256 threads = 4 waves (each 64x64, 4x4 of 16x16x32).
// Double-buffered LDS. B via global_load_lds (pre-packed/pre-swizzled),
// A via reg-staging (fp32 load -> bf16 cvt -> swizzled ds_write), T14 split.
// ---------------------------------------------------------------------------
__global__ __launch_bounds__(256, 2) void gemm_main(
    const float* __restrict__ x, const unsigned short* __restrict__ WcPack,
    const float* __restrict__ b_proj, float* __restrict__ out)
{
  __shared__ unsigned short Alds[2][128 * 64];   // [row][k] bf16, swizzled
  __shared__ unsigned short Blds[2][128 * 64];   // [col][k] bf16, swizzled

  const int tid = threadIdx.x;
  const int bid = blockIdx.x;
  const int m0 = (bid >> 2) << 7;                // 512 row-groups
  const int ct = bid & 3;                        // 4 col-tiles (siblings adjacent -> L2/L3 reuse of A)
  const int n0 = ct << 7;

  const int lane = tid & 63;
  const int wave = tid >> 6;
  const int wr = wave >> 1, wc = wave & 1;
  const int l15 = lane & 15, l4 = lane >> 4;

  f32x4 acc[4][4] = {};

  const int arow = tid >> 4;                     // staging: 16 rows/pass
  const int af4 = tid & 15;                      // float4 slot in row (64 floats)

  auto issueB = [&](int bufi, int kt) {
    const char* g = reinterpret_cast<const char*>(WcPack) + (((ct << 3) + kt) << 14);
    char* l = reinterpret_cast<char*>(&Blds[bufi][0]);
    #pragma unroll
    for (int i = 0; i < 4; ++i) {
      const int off = (i << 12) + (tid << 4);
      __builtin_amdgcn_global_load_lds(
          (__attribute__((address_space(1))) void*)(void*)(g + off),
          (__attribute__((address_space(3))) void*)(void*)(l + off),
          16, 0, 0);
    }
  };
  auto loadA = [&](int kt, f32x4* tmp) {
    const float* src = x + (size_t)m0 * 1024 + (kt << 6);
    #pragma unroll
    for (int p = 0; p < 8; ++p) {
      const int row = arow + (p << 4);
      tmp[p] = *reinterpret_cast<const f32x4*>(src + (size_t)row * 1024 + (af4 << 2));
    }
  };
  auto writeA = [&](int bufi, const f32x4* tmp) {
    char* base = reinterpret_cast<char*>(&Alds[bufi][0]);
    #pragma unroll
    for (int p = 0; p < 8; ++p) {
      const int row = arow + (p << 4);
      const uint32_t boff = (uint32_t)(((row << 7) + (af4 << 3)) ^ ((row & 7) << 4));
      u16x4 h;
      h.x = f2bf(tmp[p][0]); h.y = f2bf(tmp[p][1]);
      h.z = f2bf(tmp[p][2]); h.w = f2bf(tmp[p][3]);
      *reinterpret_cast<u16x4*>(base + boff) = h;
    }
  };
  auto compute = [&](int bufi) {
    const char* Ab = reinterpret_cast<const char*>(&Alds[bufi][0]);
    const char* Bb = reinterpret_cast<const char*>(&Blds[bufi][0]);
    #pragma unroll
    for (int ks = 0; ks < 2; ++ks) {             // two K=32 halves of BK=64
      bf16x8 afr[4], bfr[4];
      #pragma unroll
      for (int i = 0; i < 4; ++i) {
        const int ar = (wr << 6) + (i << 4) + l15;
        const uint32_t ao = (uint32_t)(((ar << 7) + (ks << 6) + (l4 << 4)) ^ ((ar & 7) << 4));
        afr[i] = *reinterpret_cast<const bf16x8*>(Ab + ao);
        const int bc = (wc << 6) + (i << 4) + l15;
        const uint32_t bo = (uint32_t)(((bc << 7) + (ks << 6) + (l4 << 4)) ^ ((bc & 7) << 4));
        bfr[i] = *reinterpret_cast<const bf16x8*>(Bb + bo);
      }
      #pragma unroll
      for (int mi = 0; mi < 4; ++mi)
        #pragma unroll
        for (int ni = 0; ni < 4; ++ni)
          acc[mi][ni] = __builtin_amdgcn_mfma_f32_16x16x32_bf16(
              afr[mi], bfr[ni], acc[mi][ni], 0, 0, 0);
    }
  };

  // prologue: stage tile 0
  {
    f32x4 tmp[8];
    issueB(0, 0);
    loadA(0, tmp);
    writeA(0, tmp);
  }
  __syncthreads();

  int buf = 0;
  for (int kt = 0; kt < 8; ++kt) {
    f32x4 nxt[8];
    if (kt < 7) { issueB(buf ^ 1, kt + 1); loadA(kt + 1, nxt); }  // async, hides under compute
    compute(buf);
    if (kt < 7) writeA(buf ^ 1, nxt);                              // cvt+write after compute (T14)
    __syncthreads();
    buf ^= 1;
  }

  // epilogue: bias + store. C/D layout: col = lane&15, row = (lane>>4)*4 + reg
  const int cbase = n0 + (wc << 6) + l15;
  float bias[4];
  #pragma unroll
  for (int ni = 0; ni < 4; ++ni) bias[ni] = b_proj[cbase + (ni << 4)];
  const int rbase = m0 + (wr << 6) + (l4 << 2);
  #pragma unroll
  for (int mi = 0; mi < 4; ++mi) {
    #pragma unroll
    for (int ni = 0; ni < 4; ++ni) {
      const int cg = cbase + (ni << 4);
      #pragma unroll
      for (int rg = 0; rg < 4; ++rg) {
        const int row = rbase + (mi << 4) + rg;
        out[(size_t)row * 512 + cg] = acc[mi][ni][rg] + bias[ni];
      }
    }
  }
}

extern "C" void kernel_launch(void* const* d_in, const int* in_sizes, int n_in,
                              void* d_out, int out_size, void* d_ws, size_t ws_size,
                              hipStream_t stream) {
  const float* x      = (const float*)d_in[0];   // (65536, 2, 512) fp32
  const float* W_kv   = (const float*)d_in[1];   // (512, 1024) fp32
  const float* W_proj = (const float*)d_in[2];   // (512, 512) fp32
  const float* b_proj = (const float*)d_in[3];   // (512,) fp32
  float* out = (float*)d_out;                    // (65536, 1, 512) fp32
  unsigned short* WcPack = (unsigned short*)d_ws; // 512 KB packed bf16 Wc

  prep_wc<<<128, 256, 0, stream>>>(W_kv, W_proj, WcPack);
  gemm_main<<<2048, 256, 0, stream>>>(x, WcPack, b_proj, out);
}

// Round 3
// 454.983 us; speedup vs baseline: 1.0905x; 1.0905x over previous
//
#include <hip/hip_runtime.h>
#include <stdint.h>

typedef __attribute__((ext_vector_type(4))) float f32x4;
typedef __attribute__((ext_vector_type(8))) __bf16 bf16x8;
typedef __attribute__((ext_vector_type(4))) __bf16 bf16x4;

static __device__ __forceinline__ unsigned short f2bf(float f) {
  union { float f; uint32_t u; } v; v.f = f;
  return (unsigned short)((v.u + 0x7fffu + ((v.u >> 16) & 1u)) >> 16);  // RNE
}

// ---------------------------------------------------------------------------
// Kernel 1: Wc[k][n] = sum_c W_kv[k][512+c] * W_proj[c][n]   (fp32 accum)
// Output packed bf16 in the exact LDS byte image gemm_main stages with
// global_load_lds: tile (ct=n>>7, ks=k>>6) of 16384 B; within tile, element
// (col=n&127, kk=k&63) at byte ((col*128 + kk*2) ^ ((col&7)<<4)).
// v2: c-loop split into two interleaved halves -> 2x MLP (latency-bound fix).
// ---------------------------------------------------------------------------
__global__ __launch_bounds__(256) void prep_wc(
    const float* __restrict__ W_kv, const float* __restrict__ W_proj,
    unsigned short* __restrict__ WcPack)
{
  const int t = threadIdx.x;
  const int k0 = blockIdx.x * 4;                 // 128 blocks cover k 0..511
  const int col = t & 127;
  const int n = col * 4;
  const int kj = __builtin_amdgcn_readfirstlane((t >> 7) * 2);  // wave-uniform
  const float* __restrict__ wv0 = W_kv + (size_t)(k0 + kj) * 1024 + 512;
  const float* __restrict__ wv1 = wv0 + 1024;

  float a0a[4] = {}, a0b[4] = {}, a1a[4] = {}, a1b[4] = {};
  #pragma unroll 4
  for (int c = 0; c < 256; ++c) {
    const float s0 = wv0[c],        s1 = wv1[c];
    const float t0 = wv0[c + 256],  t1 = wv1[c + 256];
    const f32x4 p = *reinterpret_cast<const f32x4*>(W_proj + (size_t)c * 512 + n);
    const f32x4 q = *reinterpret_cast<const f32x4*>(W_proj + (size_t)(c + 256) * 512 + n);
    #pragma unroll
    for (int i = 0; i < 4; ++i) {
      a0a[i] += s0 * p[i]; a1a[i] += s1 * p[i];
      a0b[i] += t0 * q[i]; a1b[i] += t1 * q[i];
    }
  }

  #pragma unroll
  for (int j = 0; j < 2; ++j) {
    const int k = k0 + kj + j;
    const int ks = k >> 6, kk = k & 63;
    #pragma unroll
    for (int i = 0; i < 4; ++i) {
      const float val = j ? (a1a[i] + a1b[i]) : (a0a[i] + a0b[i]);
      const int nn = n + i;
      const int ct = nn >> 7, cc = nn & 127;
      const uint32_t boff = (uint32_t)(((cc << 7) + (kk << 1)) ^ ((cc & 7) << 4));
      WcPack[(size_t)(((ct << 3) + ks) << 13) + (boff >> 1)] = f2bf(val);
    }
  }
}

// ---------------------------------------------------------------------------
// Kernel 2: out[m][n] = x[m*1024 + k] (k<512) @ Wc[k][n] + b_proj[n]
// 128x128 tile, BK=64, 256 threads = 4 waves (each 64x64, 4x4 of 16x16x32).
// Double-buffered LDS. B via global_load_lds (pre-packed/pre-swizzled),
// A via reg-staging (fp32 load -> v_cvt_pk_bf16 -> swizzled ds_write), T14.
// v2: bijective XCD swizzle so the 4 col-tile siblings of each row-group
// land on ONE XCD (A-panel L2 reuse); compiler bf16 casts replace manual RNE.
// ---------------------------------------------------------------------------
__global__ __launch_bounds__(256, 2) void gemm_main(
    const float* __restrict__ x, const unsigned short* __restrict__ WcPack,
    const float* __restrict__ b_proj, float* __restrict__ out)
{
  __shared__ unsigned short Alds[2][128 * 64];   // [row][k] bf16, swizzled
  __shared__ unsigned short Blds[2][128 * 64];   // [col][k] bf16, swizzled

  const int tid = threadIdx.x;
  // XCD-bijective swizzle: grid=2048, 8 XCDs, 256 logical tiles per XCD.
  // Siblings (same row-group, ct=0..3) become consecutive logicals on the
  // same XCD -> A panel (256 KB) is fetched once into that XCD's L2.
  const int rawb = (int)blockIdx.x;
  const int bid = ((rawb & 7) << 8) + (rawb >> 3);
  const int m0 = (bid >> 2) << 7;                // 512 row-groups
  const int ct = bid & 3;                        // 4 col-tiles
  const int n0 = ct << 7;

  const int lane = tid & 63;
  const int wave = tid >> 6;
  const int wr = wave >> 1, wc = wave & 1;
  const int l15 = lane & 15, l4 = lane >> 4;

  f32x4 acc[4][4] = {};

  const int arow = tid >> 4;                     // staging: 16 rows/pass
  const int af4 = tid & 15;                      // float4 slot in row

  auto issueB = [&](int bufi, int kt) {
    const char* g = reinterpret_cast<const char*>(WcPack) + (((ct << 3) + kt) << 14);
    char* l = reinterpret_cast<char*>(&Blds[bufi][0]);
    #pragma unroll
    for (int i = 0; i < 4; ++i) {
      const int off = (i << 12) + (tid << 4);
      __builtin_amdgcn_global_load_lds(
          (__attribute__((address_space(1))) void*)(void*)(g + off),
          (__attribute__((address_space(3))) void*)(void*)(l + off),
          16, 0, 0);
    }
  };
  auto loadA = [&](int kt, f32x4* tmp) {
    const float* src = x + (size_t)m0 * 1024 + (kt << 6);
    #pragma unroll
    for (int p = 0; p < 8; ++p) {
      const int row = arow + (p << 4);
      tmp[p] = *reinterpret_cast<const f32x4*>(src + (size_t)row * 1024 + (af4 << 2));
    }
  };
  auto writeA = [&](int bufi, const f32x4* tmp) {
    char* base = reinterpret_cast<char*>(&Alds[bufi][0]);
    #pragma unroll
    for (int p = 0; p < 8; ++p) {
      const int row = arow + (p << 4);
      const uint32_t boff = (uint32_t)(((row << 7) + (af4 << 3)) ^ ((row & 7) << 4));
      bf16x4 h;
      h[0] = (__bf16)tmp[p][0]; h[1] = (__bf16)tmp[p][1];
      h[2] = (__bf16)tmp[p][2]; h[3] = (__bf16)tmp[p][3];
      *reinterpret_cast<bf16x4*>(base + boff) = h;
    }
  };
  auto compute = [&](int bufi) {
    const char* Ab = reinterpret_cast<const char*>(&Alds[bufi][0]);
    const char* Bb = reinterpret_cast<const char*>(&Blds[bufi][0]);
    #pragma unroll
    for (int ks = 0; ks < 2; ++ks) {             // two K=32 halves of BK=64
      bf16x8 afr[4], bfr[4];
      #pragma unroll
      for (int i = 0; i < 4; ++i) {
        const int ar = (wr << 6) + (i << 4) + l15;
        const uint32_t ao = (uint32_t)(((ar << 7) + (ks << 6) + (l4 << 4)) ^ ((ar & 7) << 4));
        afr[i] = *reinterpret_cast<const bf16x8*>(Ab + ao);
        const int bc = (wc << 6) + (i << 4) + l15;
        const uint32_t bo = (uint32_t)(((bc << 7) + (ks << 6) + (l4 << 4)) ^ ((bc & 7) << 4));
        bfr[i] = *reinterpret_cast<const bf16x8*>(Bb + bo);
      }
      #pragma unroll
      for (int mi = 0; mi < 4; ++mi)
        #pragma unroll
        for (int ni = 0; ni < 4; ++ni)
          acc[mi][ni] = __builtin_amdgcn_mfma_f32_16x16x32_bf16(
              afr[mi], bfr[ni], acc[mi][ni], 0, 0, 0);
    }
  };

  // prologue: stage tile 0
  {
    f32x4 tmp[8];
    issueB(0, 0);
    loadA(0, tmp);
    writeA(0, tmp);
  }
  __syncthreads();

  int buf = 0;
  for (int kt = 0; kt < 8; ++kt) {
    f32x4 nxt[8];
    if (kt < 7) { issueB(buf ^ 1, kt + 1); loadA(kt + 1, nxt); }  // async, hides under compute
    compute(buf);
    if (kt < 7) writeA(buf ^ 1, nxt);                              // cvt+write after compute (T14)
    __syncthreads();
    buf ^= 1;
  }

  // epilogue: bias + store. C/D layout: col = lane&15, row = (lane>>4)*4 + reg
  const int cbase = n0 + (wc << 6) + l15;
  float bias[4];
  #pragma unroll
  for (int ni = 0; ni < 4; ++ni) bias[ni] = b_proj[cbase + (ni << 4)];
  const int rbase = m0 + (wr << 6) + (l4 << 2);
  #pragma unroll
  for (int mi = 0; mi < 4; ++mi) {
    #pragma unroll
    for (int ni = 0; ni < 4; ++ni) {
      const int cg = cbase + (ni << 4);
      #pragma unroll
      for (int rg = 0; rg < 4; ++rg) {
        const int row = rbase + (mi << 4) + rg;
        out[(size_t)row * 512 + cg] = acc[mi][ni][rg] + bias[ni];
      }
    }
  }
}

extern "C" void kernel_launch(void* const* d_in, const int* in_sizes, int n_in,
                              void* d_out, int out_size, void* d_ws, size_t ws_size,
                              hipStream_t stream) {
  const float* x      = (const float*)d_in[0];   // (65536, 2, 512) fp32
  const float* W_kv   = (const float*)d_in[1];   // (512, 1024) fp32
  const float* W_proj = (const float*)d_in[2];   // (512, 512) fp32
  const float* b_proj = (const float*)d_in[3];   // (512,) fp32
  float* out = (float*)d_out;                    // (65536, 1, 512) fp32
  unsigned short* WcPack = (unsigned short*)d_ws; // 512 KB packed bf16 Wc

  prep_wc<<<128, 256, 0, stream>>>(W_kv, W_proj, WcPack);
  gemm_main<<<2048, 256, 0, stream>>>(x, WcPack, b_proj, out);
}

// Round 4
// 450.936 us; speedup vs baseline: 1.1003x; 1.0090x over previous
//
#include <hip/hip_runtime.h>
#include <stdint.h>

typedef __attribute__((ext_vector_type(4))) float f32x4;
typedef __attribute__((ext_vector_type(8))) __bf16 bf16x8;
typedef __attribute__((ext_vector_type(4))) __bf16 bf16x4;

static __device__ __forceinline__ unsigned short f2bf(float f) {
  union { float f; uint32_t u; } v; v.f = f;
  return (unsigned short)((v.u + 0x7fffu + ((v.u >> 16) & 1u)) >> 16);  // RNE
}

// ---------------------------------------------------------------------------
// Kernel 1: Wc[k][n] = sum_c W_kv[k][512+c] * W_proj[c][n]   (fp32 accum)
// Output packed bf16 in the exact LDS byte image gemm_main stages with
// global_load_lds: tile (ct=n>>7, ks=k>>6) of 16384 B; within tile, element
// (col=n&127, kk=k&63) at byte ((col*128 + kk*2) ^ ((col&7)<<4)).
// ---------------------------------------------------------------------------
__global__ __launch_bounds__(256) void prep_wc(
    const float* __restrict__ W_kv, const float* __restrict__ W_proj,
    unsigned short* __restrict__ WcPack)
{
  const int t = threadIdx.x;
  const int k0 = blockIdx.x * 4;                 // 128 blocks cover k 0..511
  const int col = t & 127;
  const int n = col * 4;
  const int kj = __builtin_amdgcn_readfirstlane((t >> 7) * 2);  // wave-uniform
  const float* __restrict__ wv0 = W_kv + (size_t)(k0 + kj) * 1024 + 512;
  const float* __restrict__ wv1 = wv0 + 1024;

  float a0a[4] = {}, a0b[4] = {}, a1a[4] = {}, a1b[4] = {};
  #pragma unroll 4
  for (int c = 0; c < 256; ++c) {
    const float s0 = wv0[c],        s1 = wv1[c];
    const float t0 = wv0[c + 256],  t1 = wv1[c + 256];
    const f32x4 p = *reinterpret_cast<const f32x4*>(W_proj + (size_t)c * 512 + n);
    const f32x4 q = *reinterpret_cast<const f32x4*>(W_proj + (size_t)(c + 256) * 512 + n);
    #pragma unroll
    for (int i = 0; i < 4; ++i) {
      a0a[i] += s0 * p[i]; a1a[i] += s1 * p[i];
      a0b[i] += t0 * q[i]; a1b[i] += t1 * q[i];
    }
  }

  #pragma unroll
  for (int j = 0; j < 2; ++j) {
    const int k = k0 + kj + j;
    const int ks = k >> 6, kk = k & 63;
    #pragma unroll
    for (int i = 0; i < 4; ++i) {
      const float val = j ? (a1a[i] + a1b[i]) : (a0a[i] + a0b[i]);
      const int nn = n + i;
      const int ct = nn >> 7, cc = nn & 127;
      const uint32_t boff = (uint32_t)(((cc << 7) + (kk << 1)) ^ ((cc & 7) << 4));
      WcPack[(size_t)(((ct << 3) + ks) << 13) + (boff >> 1)] = f2bf(val);
    }
  }
}

// ---------------------------------------------------------------------------
// Kernel 2: out[m][n] = x[m*1024 + k] (k<512) @ Wc[k][n] + b_proj[n]
// 128x128 tile, BK=64, 4 waves (each 64x64, 4x4 of 16x16x32).
// v3: counted-vmcnt pipeline (T3/T4). B triple-buffered via global_load_lds
// issued TWO tiles ahead; A double-buffered reg-staging issued one ahead.
// Raw s_barrier + vmcnt(4) steady state -> 4 B-loads stay in flight across
// every barrier (no full drain). Loop fully unrolled (static buf indices).
// ---------------------------------------------------------------------------
__global__ __launch_bounds__(256, 2) void gemm_main(
    const float* __restrict__ x, const unsigned short* __restrict__ WcPack,
    const float* __restrict__ b_proj, float* __restrict__ out)
{
  __shared__ __align__(16) unsigned short Alds[2][128 * 64];  // [row][k] bf16, swz
  __shared__ __align__(16) unsigned short Blds[3][128 * 64];  // [col][k] bf16, swz

  const int tid = threadIdx.x;
  // XCD-bijective swizzle: grid=2048, 8 XCDs, 256 logical tiles per XCD.
  const int rawb = (int)blockIdx.x;
  const int bid = ((rawb & 7) << 8) + (rawb >> 3);
  const int m0 = (bid >> 2) << 7;                // 512 row-groups
  const int ct = bid & 3;                        // 4 col-tiles (A L2 reuse)
  const int n0 = ct << 7;

  const int lane = tid & 63;
  const int wave = tid >> 6;
  const int wr = wave >> 1, wc = wave & 1;
  const int l15 = lane & 15, l4 = lane >> 4;

  f32x4 acc[4][4] = {};

  const int arow = tid >> 4;                     // staging: 16 rows/pass
  const int af4 = tid & 15;                      // float4 slot in row

  auto issueB = [&](int bufi, int kt) {
    const char* g = reinterpret_cast<const char*>(WcPack) + (((ct << 3) + kt) << 14);
    char* l = reinterpret_cast<char*>(&Blds[bufi][0]);
    #pragma unroll
    for (int i = 0; i < 4; ++i) {
      const int off = (i << 12) + (tid << 4);
      __builtin_amdgcn_global_load_lds(
          (__attribute__((address_space(1))) void*)(void*)(g + off),
          (__attribute__((address_space(3))) void*)(void*)(l + off),
          16, 0, 0);
    }
  };
  auto loadA = [&](int kt, f32x4* tmp) {
    const float* src = x + (size_t)m0 * 1024 + (kt << 6);
    #pragma unroll
    for (int p = 0; p < 8; ++p) {
      const int row = arow + (p << 4);
      tmp[p] = *reinterpret_cast<const f32x4*>(src + (size_t)row * 1024 + (af4 << 2));
    }
  };
  auto writeA = [&](int bufi, const f32x4* tmp) {
    char* base = reinterpret_cast<char*>(&Alds[bufi][0]);
    #pragma unroll
    for (int p = 0; p < 8; ++p) {
      const int row = arow + (p << 4);
      const uint32_t boff = (uint32_t)(((row << 7) + (af4 << 3)) ^ ((row & 7) << 4));
      bf16x4 h;
      h[0] = (__bf16)tmp[p][0]; h[1] = (__bf16)tmp[p][1];
      h[2] = (__bf16)tmp[p][2]; h[3] = (__bf16)tmp[p][3];
      *reinterpret_cast<bf16x4*>(base + boff) = h;
    }
  };
  auto compute = [&](int abuf, int bbuf) {
    const char* Ab = reinterpret_cast<const char*>(&Alds[abuf][0]);
    const char* Bb = reinterpret_cast<const char*>(&Blds[bbuf][0]);
    #pragma unroll
    for (int ks = 0; ks < 2; ++ks) {             // two K=32 halves of BK=64
      bf16x8 afr[4], bfr[4];
      #pragma unroll
      for (int i = 0; i < 4; ++i) {
        const int ar = (wr << 6) + (i << 4) + l15;
        const uint32_t ao = (uint32_t)(((ar << 7) + (ks << 6) + (l4 << 4)) ^ ((ar & 7) << 4));
        afr[i] = *reinterpret_cast<const bf16x8*>(Ab + ao);
        const int bc = (wc << 6) + (i << 4) + l15;
        const uint32_t bo = (uint32_t)(((bc << 7) + (ks << 6) + (l4 << 4)) ^ ((bc & 7) << 4));
        bfr[i] = *reinterpret_cast<const bf16x8*>(Bb + bo);
      }
      #pragma unroll
      for (int mi = 0; mi < 4; ++mi)
        #pragma unroll
        for (int ni = 0; ni < 4; ++ni)
          acc[mi][ni] = __builtin_amdgcn_mfma_f32_16x16x32_bf16(
              afr[mi], bfr[ni], acc[mi][ni], 0, 0, 0);
    }
  };

  // ---- prologue: B(0),A(0) staged; B(1) left in flight across the barrier
  {
    f32x4 tmp[8];
    issueB(0, 0);                                // 4 vm (oldest)
    loadA(0, tmp);                               // 8 vm
    issueB(1, 1);                                // 4 vm (newest)
    asm volatile("s_waitcnt vmcnt(4)" ::: "memory");  // B0+A0 done; B1 in flight
    writeA(0, tmp);
    asm volatile("s_waitcnt lgkmcnt(0)" ::: "memory");
    __builtin_amdgcn_s_barrier();
    asm volatile("" ::: "memory");
  }

  // ---- main loop: compute(kt) while A(kt+1) lands and B(kt+2) is issued
  #pragma unroll
  for (int kt = 0; kt < 7; ++kt) {
    f32x4 nxt[8];
    loadA(kt + 1, nxt);                          // 8 vm
    if (kt < 6) issueB((kt + 2) % 3, kt + 2);    // 4 vm (newest)
    compute(kt & 1, kt % 3);
    if (kt < 6) asm volatile("s_waitcnt vmcnt(4)" ::: "memory");  // keep B(kt+2) in flight
    else        asm volatile("s_waitcnt vmcnt(0)" ::: "memory");
    writeA((kt + 1) & 1, nxt);
    asm volatile("s_waitcnt lgkmcnt(0)" ::: "memory");
    __builtin_amdgcn_s_barrier();
    asm volatile("" ::: "memory");
  }
  compute(7 & 1, 7 % 3);

  // epilogue: bias + store. C/D layout: col = lane&15, row = (lane>>4)*4 + reg
  const int cbase = n0 + (wc << 6) + l15;
  float bias[4];
  #pragma unroll
  for (int ni = 0; ni < 4; ++ni) bias[ni] = b_proj[cbase + (ni << 4)];
  const int rbase = m0 + (wr << 6) + (l4 << 2);
  #pragma unroll
  for (int mi = 0; mi < 4; ++mi) {
    #pragma unroll
    for (int ni = 0; ni < 4; ++ni) {
      const int cg = cbase + (ni << 4);
      #pragma unroll
      for (int rg = 0; rg < 4; ++rg) {
        const int row = rbase + (mi << 4) + rg;
        out[(size_t)row * 512 + cg] = acc[mi][ni][rg] + bias[ni];
      }
    }
  }
}

extern "C" void kernel_launch(void* const* d_in, const int* in_sizes, int n_in,
                              void* d_out, int out_size, void* d_ws, size_t ws_size,
                              hipStream_t stream) {
  const float* x      = (const float*)d_in[0];   // (65536, 2, 512) fp32
  const float* W_kv   = (const float*)d_in[1];   // (512, 1024) fp32
  const float* W_proj = (const float*)d_in[2];   // (512, 512) fp32
  const float* b_proj = (const float*)d_in[3];   // (512,) fp32
  float* out = (float*)d_out;                    // (65536, 1, 512) fp32
  unsigned short* WcPack = (unsigned short*)d_ws; // 512 KB packed bf16 Wc

  prep_wc<<<128, 256, 0, stream>>>(W_kv, W_proj, WcPack);
  gemm_main<<<2048, 256, 0, stream>>>(x, WcPack, b_proj, out);
}